// Round 10
// baseline (174.663 us; speedup 1.0000x reference)
//
#include <hip/hip_runtime.h>
#include <hip/hip_bf16.h>

#define IMG   512
#define TW    64
#define TH    32
#define WS    11
#define NP    96
#define NSLOT 256
#define PR    21            // pair-rows (42 h-conv rows as bf16 pairs)
#define PLANE (PR*64)       // u32 words per signal plane (1344)

static __device__ __forceinline__ ushort f2bf(float x) {
    __hip_bfloat16 h = __float2bfloat16(x);
    return __builtin_bit_cast(ushort, h);
}
static __device__ __forceinline__ uint pkbf(float ev, float od) {
    return (uint)f2bf(ev) | ((uint)f2bf(od) << 16);
}
static __device__ __forceinline__ float bfval(ushort u) {
    return __builtin_bit_cast(float, (uint)u << 16);
}

__global__ __launch_bounds__(256, 6) void ssim_main(const float* __restrict__ img1,
                                                    const float* __restrict__ img2,
                                                    double* __restrict__ acc) {
    constexpr float W[WS] = {
        0.00102837990674f, 0.00759883148699f, 0.03600079242909f,
        0.10936069869137f, 0.21300538108707f, 0.26601190869814f,
        0.21300538108707f, 0.10936069869137f, 0.03600079242909f,
        0.00759883148699f, 0.00102837990674f };

    // 5 signal planes, bf16 row-pairs: HP[(s*PR+p)*64 + col] = bf16(H[2p]) | bf16(H[2p+1])<<16
    __shared__ uint HP[5 * PLANE];   // 26,880 B -> 6 blocks/CU

    const int tid = threadIdx.x;
    const int bx = blockIdx.x;   // 0..7
    const int by = blockIdx.y;   // 0..15
    const float* p1 = img1 + (size_t)blockIdx.z * (IMG * IMG);
    const float* p2 = img2 + (size_t)blockIdx.z * (IMG * IMG);

    // bf16-rounded vertical weights, packed pairs for dot2; alpha = their sum
    ushort us[12];
    #pragma unroll
    for (int t = 0; t < WS; ++t) us[t] = f2bf(W[t]);
    us[11] = 0;
    float alpha = 0.f;
    #pragma unroll
    for (int t = 0; t < WS; ++t) alpha += bfval(us[t]);
    uint pe[6], po[6];
    #pragma unroll
    for (int j = 0; j < 6; ++j) {
        pe[j] = (uint)us[2*j] | ((uint)us[2*j+1] << 16);           // even out-row: taps 2j, 2j+1
        po[j] = (j ? (uint)us[2*j-1] : 0u) | ((uint)us[2*j] << 16); // odd out-row: taps 2j-1, 2j
    }

    // ---------- Phase 1: horizontal conv, 2 rows x 4 cols per unit ----------
    for (int u = tid; u < PR * 16; u += 256) {        // 336 units
        const int pr = u >> 4;        // pair-row 0..20
        const int cg = u & 15;        // 4-col group

        float A[5][2][4];
        #pragma unroll
        for (int s = 0; s < 5; ++s)
            #pragma unroll
            for (int rw = 0; rw < 2; ++rw)
                #pragma unroll
                for (int o = 0; o < 4; ++o) A[s][rw][o] = 0.f;

        #pragma unroll
        for (int rw = 0; rw < 2; ++rw) {
            const int gy = by * TH + 2 * pr + rw - 5;
            const bool rowOK = (unsigned)gy < IMG;
            const float* r1 = p1 + (size_t)gy * IMG;
            const float* r2 = p2 + (size_t)gy * IMG;
            #pragma unroll
            for (int j = 0; j < 5; ++j) {
                const int gx = bx * TW + cg * 4 - 8 + 4 * j;
                float4 X = make_float4(0.f,0.f,0.f,0.f), Y = X;
                if (rowOK && (unsigned)gx < IMG) {
                    X = *(const float4*)(r1 + gx);
                    Y = *(const float4*)(r2 + gx);
                }
                const float e1[4] = {X.x,X.y,X.z,X.w};
                const float e2[4] = {Y.x,Y.y,Y.z,Y.w};
                #pragma unroll
                for (int e = 0; e < 4; ++e) {
                    const int i = 4*j + e;            // taps live 3..16
                    if (i < 3 || i > 16) continue;
                    const float x1 = e1[e], x2 = e2[e];
                    const float q11 = x1*x1, q22 = x2*x2, q12 = x1*x2;
                    #pragma unroll
                    for (int o = 0; o < 4; ++o) {
                        const int t = i - 3 - o;
                        if (t >= 0 && t < WS) {
                            A[0][rw][o] += W[t]*x1;  A[1][rw][o] += W[t]*x2;
                            A[2][rw][o] += W[t]*q11; A[3][rw][o] += W[t]*q22;
                            A[4][rw][o] += W[t]*q12;
                        }
                    }
                }
            }
        }

        #pragma unroll
        for (int s = 0; s < 5; ++s) {
            const uint4 pv = make_uint4(pkbf(A[s][0][0], A[s][1][0]),
                                        pkbf(A[s][0][1], A[s][1][1]),
                                        pkbf(A[s][0][2], A[s][1][2]),
                                        pkbf(A[s][0][3], A[s][1][3]));
            *(uint4*)&HP[(s * PR + pr) * 64 + cg * 4] = pv;
        }
    }
    __syncthreads();

    // ---------- Phase 2: vertical conv via v_dot2_f32_bf16 ------------------
    const int q0 = tid >> 4;     // out row-pair (rows 2q0, 2q0+1)
    const int cg = tid & 15;     // 4-col group

    float m[5][2][4];
    #pragma unroll
    for (int s = 0; s < 5; ++s)
        #pragma unroll
        for (int pth = 0; pth < 2; ++pth)
            #pragma unroll
            for (int c = 0; c < 4; ++c) m[s][pth][c] = 0.f;

    #pragma unroll
    for (int s = 0; s < 5; ++s) {
        #pragma unroll
        for (int j = 0; j <= 5; ++j) {
            const uint4 v = *(const uint4*)&HP[(s * PR + q0 + j) * 64 + cg * 4];
            const uint vv[4] = {v.x, v.y, v.z, v.w};
            #pragma unroll
            for (int c = 0; c < 4; ++c) {
                asm("v_dot2_f32_bf16 %0, %1, %2, %0"
                    : "+v"(m[s][0][c]) : "v"(vv[c]), "v"(pe[j]));
                asm("v_dot2_f32_bf16 %0, %1, %2, %0"
                    : "+v"(m[s][1][c]) : "v"(vv[c]), "v"(po[j]));
            }
        }
    }

    // ---------- Epilogue: kernel-sum correction + SSIM for 8 px -------------
    const float invA = 1.0f / alpha;
    const float C1 = 0.01f*0.01f, C2 = 0.03f*0.03f;
    float lsum = 0.f;
    #pragma unroll
    for (int pth = 0; pth < 2; ++pth) {
        #pragma unroll
        for (int c = 0; c < 4; ++c) {
            const float mu1 = m[0][pth][c] * invA, mu2 = m[1][pth][c] * invA;
            const float m11 = m[2][pth][c] * invA, m22 = m[3][pth][c] * invA;
            const float m12 = m[4][pth][c] * invA;
            const float mu1s = mu1*mu1, mu2s = mu2*mu2, mu12 = mu1*mu2;
            const float s11 = m11 - mu1s;
            const float s22 = m22 - mu2s;
            const float s12 = m12 - mu12;
            const float num = (2.f*mu12 + C1) * (2.f*s12 + C2);
            const float den = (mu1s + mu2s + C1) * (s11 + s22 + C2);
            lsum += num * __builtin_amdgcn_rcpf(den);
        }
    }

    // wave reduce + block reduce + spread atomic
    #pragma unroll
    for (int d = 32; d >= 1; d >>= 1)
        lsum += __shfl_down(lsum, d, 64);
    __shared__ float wsum[4];
    if ((tid & 63) == 0) wsum[tid >> 6] = lsum;
    __syncthreads();
    if (tid == 0) {
        const float t = wsum[0] + wsum[1] + wsum[2] + wsum[3];
        const int bid = (blockIdx.z * gridDim.y + blockIdx.y) * gridDim.x + blockIdx.x;
        atomicAdd(&acc[bid & (NSLOT - 1)], (double)t);
    }
}

__global__ void ssim_final(const double* __restrict__ acc, float* __restrict__ out) {
    const int l = threadIdx.x;   // 64 threads
    double s = acc[l] + acc[l + 64] + acc[l + 128] + acc[l + 192];
    #pragma unroll
    for (int d = 32; d >= 1; d >>= 1)
        s += __shfl_down(s, d, 64);
    if (l == 0)
        out[0] = 1.0f - (float)(s / (double)((size_t)NP * IMG * IMG));
}

extern "C" void kernel_launch(void* const* d_in, const int* in_sizes, int n_in,
                              void* d_out, int out_size, void* d_ws, size_t ws_size,
                              hipStream_t stream) {
    const float* img1 = (const float*)d_in[0];
    const float* img2 = (const float*)d_in[1];
    float* out = (float*)d_out;
    double* acc = (double*)d_ws;

    hipMemsetAsync(d_ws, 0, NSLOT * sizeof(double), stream);

    dim3 grid(IMG / TW, IMG / TH, NP);
    ssim_main<<<grid, dim3(256), 0, stream>>>(img1, img2, acc);
    ssim_final<<<1, dim3(64), 0, stream>>>(acc, out);
}

// Round 11
// 112.947 us; speedup vs baseline: 1.5464x; 1.5464x over previous
//
#include <hip/hip_runtime.h>
#include <hip/hip_bf16.h>

#define IMG   512
#define TW    64
#define TH    32
#define WS    11
#define NP    96
#define NSLOT 256
#define PR    21            // pair-rows (42 h-conv rows as bf16 pairs)
#define PLANE (PR*64)       // u32 words per signal plane (1344)

static __device__ __forceinline__ ushort f2bf(float x) {
    __hip_bfloat16 h = __float2bfloat16(x);
    return __builtin_bit_cast(ushort, h);
}
static __device__ __forceinline__ uint pkbf(float ev, float od) {
    return (uint)f2bf(ev) | ((uint)f2bf(od) << 16);
}
static __device__ __forceinline__ float bfval(ushort u) {
    return __builtin_bit_cast(float, (uint)u << 16);
}

__global__ __launch_bounds__(256, 4) void ssim_main(const float* __restrict__ img1,
                                                    const float* __restrict__ img2,
                                                    double* __restrict__ acc) {
    constexpr float W[WS] = {
        0.00102837990674f, 0.00759883148699f, 0.03600079242909f,
        0.10936069869137f, 0.21300538108707f, 0.26601190869814f,
        0.21300538108707f, 0.10936069869137f, 0.03600079242909f,
        0.00759883148699f, 0.00102837990674f };

    // 5 signal planes, bf16 row-pairs: HP[(s*PR+p)*64 + col] = bf16(H[2p]) | bf16(H[2p+1])<<16
    __shared__ uint HP[5 * PLANE];   // 26,880 B -> 6 blocks/CU (LDS-wise)

    const int tid = threadIdx.x;
    const int bx = blockIdx.x;   // 0..7
    const int by = blockIdx.y;   // 0..15
    const float* p1 = img1 + (size_t)blockIdx.z * (IMG * IMG);
    const float* p2 = img2 + (size_t)blockIdx.z * (IMG * IMG);

    // bf16-rounded vertical weights, packed pairs for dot2; alpha = their sum
    ushort us[12];
    #pragma unroll
    for (int t = 0; t < WS; ++t) us[t] = f2bf(W[t]);
    us[11] = 0;
    float alpha = 0.f;
    #pragma unroll
    for (int t = 0; t < WS; ++t) alpha += bfval(us[t]);
    uint pe[6], po[6];
    #pragma unroll
    for (int j = 0; j < 6; ++j) {
        pe[j] = (uint)us[2*j] | ((uint)us[2*j+1] << 16);            // even out-row: taps 2j, 2j+1
        po[j] = (j ? (uint)us[2*j-1] : 0u) | ((uint)us[2*j] << 16); // odd out-row: taps 2j-1, 2j
    }

    // ---------- Phase 1: horizontal conv, 2 rows x 4 cols per unit ----------
    for (int u = tid; u < PR * 16; u += 256) {        // 336 units
        const int pr = u >> 4;        // pair-row 0..20
        const int cg = u & 15;        // 4-col group

        float A[5][2][4];
        #pragma unroll
        for (int s = 0; s < 5; ++s)
            #pragma unroll
            for (int rw = 0; rw < 2; ++rw)
                #pragma unroll
                for (int o = 0; o < 4; ++o) A[s][rw][o] = 0.f;

        #pragma unroll
        for (int rw = 0; rw < 2; ++rw) {
            const int gy = by * TH + 2 * pr + rw - 5;
            const bool rowOK = (unsigned)gy < IMG;
            const float* r1 = p1 + (size_t)gy * IMG;
            const float* r2 = p2 + (size_t)gy * IMG;
            #pragma unroll
            for (int j = 0; j < 5; ++j) {
                const int gx = bx * TW + cg * 4 - 8 + 4 * j;
                float4 X = make_float4(0.f,0.f,0.f,0.f), Y = X;
                if (rowOK && (unsigned)gx < IMG) {
                    X = *(const float4*)(r1 + gx);
                    Y = *(const float4*)(r2 + gx);
                }
                const float e1[4] = {X.x,X.y,X.z,X.w};
                const float e2[4] = {Y.x,Y.y,Y.z,Y.w};
                #pragma unroll
                for (int e = 0; e < 4; ++e) {
                    const int i = 4*j + e;            // taps live 3..16
                    if (i < 3 || i > 16) continue;
                    const float x1 = e1[e], x2 = e2[e];
                    const float q11 = x1*x1, q22 = x2*x2, q12 = x1*x2;
                    #pragma unroll
                    for (int o = 0; o < 4; ++o) {
                        const int t = i - 3 - o;
                        if (t >= 0 && t < WS) {
                            A[0][rw][o] += W[t]*x1;  A[1][rw][o] += W[t]*x2;
                            A[2][rw][o] += W[t]*q11; A[3][rw][o] += W[t]*q22;
                            A[4][rw][o] += W[t]*q12;
                        }
                    }
                }
            }
        }

        #pragma unroll
        for (int s = 0; s < 5; ++s) {
            const uint4 pv = make_uint4(pkbf(A[s][0][0], A[s][1][0]),
                                        pkbf(A[s][0][1], A[s][1][1]),
                                        pkbf(A[s][0][2], A[s][1][2]),
                                        pkbf(A[s][0][3], A[s][1][3]));
            *(uint4*)&HP[(s * PR + pr) * 64 + cg * 4] = pv;
        }
    }
    __syncthreads();

    // ---------- Phase 2: vertical conv via v_dot2_f32_bf16 ------------------
    const int q0 = tid >> 4;     // out row-pair (rows 2q0, 2q0+1)
    const int cg = tid & 15;     // 4-col group

    float m[5][2][4];
    #pragma unroll
    for (int s = 0; s < 5; ++s)
        #pragma unroll
        for (int pth = 0; pth < 2; ++pth)
            #pragma unroll
            for (int c = 0; c < 4; ++c) m[s][pth][c] = 0.f;

    #pragma unroll
    for (int s = 0; s < 5; ++s) {
        #pragma unroll
        for (int j = 0; j <= 5; ++j) {
            const uint4 v = *(const uint4*)&HP[(s * PR + q0 + j) * 64 + cg * 4];
            const uint vv[4] = {v.x, v.y, v.z, v.w};
            #pragma unroll
            for (int c = 0; c < 4; ++c) {
                asm("v_dot2_f32_bf16 %0, %1, %2, %0"
                    : "+v"(m[s][0][c]) : "v"(vv[c]), "v"(pe[j]));
                asm("v_dot2_f32_bf16 %0, %1, %2, %0"
                    : "+v"(m[s][1][c]) : "v"(vv[c]), "v"(po[j]));
            }
        }
    }

    // ---------- Epilogue: kernel-sum correction + SSIM for 8 px -------------
    const float invA = 1.0f / alpha;
    const float C1 = 0.01f*0.01f, C2 = 0.03f*0.03f;
    float lsum = 0.f;
    #pragma unroll
    for (int pth = 0; pth < 2; ++pth) {
        #pragma unroll
        for (int c = 0; c < 4; ++c) {
            const float mu1 = m[0][pth][c] * invA, mu2 = m[1][pth][c] * invA;
            const float m11 = m[2][pth][c] * invA, m22 = m[3][pth][c] * invA;
            const float m12 = m[4][pth][c] * invA;
            const float mu1s = mu1*mu1, mu2s = mu2*mu2, mu12 = mu1*mu2;
            const float s11 = m11 - mu1s;
            const float s22 = m22 - mu2s;
            const float s12 = m12 - mu12;
            const float num = (2.f*mu12 + C1) * (2.f*s12 + C2);
            const float den = (mu1s + mu2s + C1) * (s11 + s22 + C2);
            lsum += num * __builtin_amdgcn_rcpf(den);
        }
    }

    // wave reduce + block reduce + spread atomic
    #pragma unroll
    for (int d = 32; d >= 1; d >>= 1)
        lsum += __shfl_down(lsum, d, 64);
    __shared__ float wsum[4];
    if ((tid & 63) == 0) wsum[tid >> 6] = lsum;
    __syncthreads();
    if (tid == 0) {
        const float t = wsum[0] + wsum[1] + wsum[2] + wsum[3];
        const int bid = (blockIdx.z * gridDim.y + blockIdx.y) * gridDim.x + blockIdx.x;
        atomicAdd(&acc[bid & (NSLOT - 1)], (double)t);
    }
}

__global__ void ssim_final(const double* __restrict__ acc, float* __restrict__ out) {
    const int l = threadIdx.x;   // 64 threads
    double s = acc[l] + acc[l + 64] + acc[l + 128] + acc[l + 192];
    #pragma unroll
    for (int d = 32; d >= 1; d >>= 1)
        s += __shfl_down(s, d, 64);
    if (l == 0)
        out[0] = 1.0f - (float)(s / (double)((size_t)NP * IMG * IMG));
}

extern "C" void kernel_launch(void* const* d_in, const int* in_sizes, int n_in,
                              void* d_out, int out_size, void* d_ws, size_t ws_size,
                              hipStream_t stream) {
    const float* img1 = (const float*)d_in[0];
    const float* img2 = (const float*)d_in[1];
    float* out = (float*)d_out;
    double* acc = (double*)d_ws;

    hipMemsetAsync(d_ws, 0, NSLOT * sizeof(double), stream);

    dim3 grid(IMG / TW, IMG / TH, NP);
    ssim_main<<<grid, dim3(256), 0, stream>>>(img1, img2, acc);
    ssim_final<<<1, dim3(64), 0, stream>>>(acc, out);
}

// Round 12
// 106.668 us; speedup vs baseline: 1.6374x; 1.0589x over previous
//
#include <hip/hip_runtime.h>
#include <hip/hip_fp16.h>

#define IMG   512
#define TW    32
#define TH    64
#define WS    11
#define NP    96
#define NSLOT 256
#define PR2   37            // pair-rows (74 h-conv rows as f16 pairs)
#define RSTR  32            // u32 row stride
#define PLANE (PR2*RSTR)    // u32 words per signal plane (1184)

typedef __attribute__((ext_vector_type(2))) _Float16 half2v;

static __device__ __forceinline__ uint pkh(float ev, float od) {
    return __builtin_bit_cast(uint, __builtin_amdgcn_cvt_pkrtz(ev, od));
}
static __device__ __forceinline__ ushort f2h(float x) {
    return __builtin_bit_cast(ushort, (_Float16)x);
}
static __device__ __forceinline__ float h2f(ushort u) {
    return (float)__builtin_bit_cast(_Float16, u);
}

__global__ __launch_bounds__(256, 4) void ssim_main(const float* __restrict__ img1,
                                                    const float* __restrict__ img2,
                                                    double* __restrict__ acc) {
    constexpr float W[WS] = {
        0.00102837990674f, 0.00759883148699f, 0.03600079242909f,
        0.10936069869137f, 0.21300538108707f, 0.26601190869814f,
        0.21300538108707f, 0.10936069869137f, 0.03600079242909f,
        0.00759883148699f, 0.00102837990674f };

    // 5 signal planes, f16 row-pairs: HP[(s*PR2+p)*32 + col] = h(H[2p]) | h(H[2p+1])<<16
    __shared__ uint HP[5 * PLANE];   // 23,680 B -> 6 blocks/CU

    const int tid = threadIdx.x;
    const int bx = blockIdx.x;   // 0..15 (x tiles, 32 wide)
    const int by = blockIdx.y;   // 0..7  (y tiles, 64 tall)
    const float* p1 = img1 + (size_t)blockIdx.z * (IMG * IMG);
    const float* p2 = img2 + (size_t)blockIdx.z * (IMG * IMG);

    // f16-rounded vertical weights, packed pairs for dot2; alpha = their sum
    ushort us[12];
    #pragma unroll
    for (int t = 0; t < WS; ++t) us[t] = f2h(W[t]);
    us[11] = 0;
    float alpha = 0.f;
    #pragma unroll
    for (int t = 0; t < WS; ++t) alpha += h2f(us[t]);
    uint pe[6], po[6];
    #pragma unroll
    for (int j = 0; j < 6; ++j) {
        pe[j] = (uint)us[2*j] | ((uint)us[2*j+1] << 16);            // even out-row: taps 2j, 2j+1
        po[j] = (j ? (uint)us[2*j-1] : 0u) | ((uint)us[2*j] << 16); // odd out-row: taps 2j-1, 2j
    }

    // ---------- Phase 1: horizontal conv (f32), 2 rows x 4 cols per unit ----
    for (int u = tid; u < PR2 * 8; u += 256) {        // 296 units
        const int pr = u >> 3;        // pair-row 0..36
        const int cg = u & 7;         // 4-col group

        float A[5][2][4];
        #pragma unroll
        for (int s = 0; s < 5; ++s)
            #pragma unroll
            for (int rw = 0; rw < 2; ++rw)
                #pragma unroll
                for (int o = 0; o < 4; ++o) A[s][rw][o] = 0.f;

        #pragma unroll
        for (int rw = 0; rw < 2; ++rw) {
            const int gy = by * TH + 2 * pr + rw - 5;
            const bool rowOK = (unsigned)gy < IMG;
            const float* r1 = p1 + (size_t)gy * IMG;
            const float* r2 = p2 + (size_t)gy * IMG;
            #pragma unroll
            for (int j = 0; j < 5; ++j) {
                const int gx = bx * TW + cg * 4 - 8 + 4 * j;
                float4 X = make_float4(0.f,0.f,0.f,0.f), Y = X;
                if (rowOK && (unsigned)gx < IMG) {
                    X = *(const float4*)(r1 + gx);
                    Y = *(const float4*)(r2 + gx);
                }
                const float e1[4] = {X.x,X.y,X.z,X.w};
                const float e2[4] = {Y.x,Y.y,Y.z,Y.w};
                #pragma unroll
                for (int e = 0; e < 4; ++e) {
                    const int i = 4*j + e;            // taps live 3..16
                    if (i < 3 || i > 16) continue;
                    const float x1 = e1[e], x2 = e2[e];
                    const float q11 = x1*x1, q22 = x2*x2, q12 = x1*x2;
                    #pragma unroll
                    for (int o = 0; o < 4; ++o) {
                        const int t = i - 3 - o;
                        if (t >= 0 && t < WS) {
                            A[0][rw][o] += W[t]*x1;  A[1][rw][o] += W[t]*x2;
                            A[2][rw][o] += W[t]*q11; A[3][rw][o] += W[t]*q22;
                            A[4][rw][o] += W[t]*q12;
                        }
                    }
                }
            }
        }

        #pragma unroll
        for (int s = 0; s < 5; ++s) {
            const uint4 pv = make_uint4(pkh(A[s][0][0], A[s][1][0]),
                                        pkh(A[s][0][1], A[s][1][1]),
                                        pkh(A[s][0][2], A[s][1][2]),
                                        pkh(A[s][0][3], A[s][1][3]));
            *(uint4*)&HP[(s * PR2 + pr) * RSTR + cg * 4] = pv;
        }
    }
    __syncthreads();

    // ---------- Phase 2: vertical conv via v_dot2_f32_f16 -------------------
    const int q0 = tid >> 3;     // out row-pair (rows 2q0, 2q0+1), 0..31
    const int cg = tid & 7;      // 4-col group

    float m[5][2][4];
    #pragma unroll
    for (int s = 0; s < 5; ++s)
        #pragma unroll
        for (int pth = 0; pth < 2; ++pth)
            #pragma unroll
            for (int c = 0; c < 4; ++c) m[s][pth][c] = 0.f;

    #pragma unroll
    for (int s = 0; s < 5; ++s) {
        #pragma unroll
        for (int j = 0; j <= 5; ++j) {
            const uint4 v = *(const uint4*)&HP[(s * PR2 + q0 + j) * RSTR + cg * 4];
            const uint vv[4] = {v.x, v.y, v.z, v.w};
            #pragma unroll
            for (int c = 0; c < 4; ++c) {
                asm("v_dot2_f32_f16 %0, %1, %2, %0"
                    : "+v"(m[s][0][c]) : "v"(vv[c]), "v"(pe[j]));
                asm("v_dot2_f32_f16 %0, %1, %2, %0"
                    : "+v"(m[s][1][c]) : "v"(vv[c]), "v"(po[j]));
            }
        }
    }

    // ---------- Epilogue: kernel-sum correction + SSIM for 8 px -------------
    const float invA = 1.0f / alpha;
    const float C1 = 0.01f*0.01f, C2 = 0.03f*0.03f;
    float lsum = 0.f;
    #pragma unroll
    for (int pth = 0; pth < 2; ++pth) {
        #pragma unroll
        for (int c = 0; c < 4; ++c) {
            const float mu1 = m[0][pth][c] * invA, mu2 = m[1][pth][c] * invA;
            const float m11 = m[2][pth][c] * invA, m22 = m[3][pth][c] * invA;
            const float m12 = m[4][pth][c] * invA;
            const float mu1s = mu1*mu1, mu2s = mu2*mu2, mu12 = mu1*mu2;
            const float s11 = m11 - mu1s;
            const float s22 = m22 - mu2s;
            const float s12 = m12 - mu12;
            const float num = (2.f*mu12 + C1) * (2.f*s12 + C2);
            const float den = (mu1s + mu2s + C1) * (s11 + s22 + C2);
            lsum += num * __builtin_amdgcn_rcpf(den);
        }
    }

    // wave reduce + block reduce + spread atomic
    #pragma unroll
    for (int d = 32; d >= 1; d >>= 1)
        lsum += __shfl_down(lsum, d, 64);
    __shared__ float wsum[4];
    if ((tid & 63) == 0) wsum[tid >> 6] = lsum;
    __syncthreads();
    if (tid == 0) {
        const float t = wsum[0] + wsum[1] + wsum[2] + wsum[3];
        const int bid = (blockIdx.z * gridDim.y + blockIdx.y) * gridDim.x + blockIdx.x;
        atomicAdd(&acc[bid & (NSLOT - 1)], (double)t);
    }
}

__global__ void ssim_final(const double* __restrict__ acc, float* __restrict__ out) {
    const int l = threadIdx.x;   // 64 threads
    double s = acc[l] + acc[l + 64] + acc[l + 128] + acc[l + 192];
    #pragma unroll
    for (int d = 32; d >= 1; d >>= 1)
        s += __shfl_down(s, d, 64);
    if (l == 0)
        out[0] = 1.0f - (float)(s / (double)((size_t)NP * IMG * IMG));
}

extern "C" void kernel_launch(void* const* d_in, const int* in_sizes, int n_in,
                              void* d_out, int out_size, void* d_ws, size_t ws_size,
                              hipStream_t stream) {
    const float* img1 = (const float*)d_in[0];
    const float* img2 = (const float*)d_in[1];
    float* out = (float*)d_out;
    double* acc = (double*)d_ws;

    hipMemsetAsync(d_ws, 0, NSLOT * sizeof(double), stream);

    dim3 grid(IMG / TW, IMG / TH, NP);
    ssim_main<<<grid, dim3(256), 0, stream>>>(img1, img2, acc);
    ssim_final<<<1, dim3(64), 0, stream>>>(acc, out);
}